// Round 21
// baseline (620.099 us; speedup 1.0000x reference)
//
#include <hip/hip_runtime.h>
#include <hip/hip_bf16.h>

#define D 128          // D_IN == D_OUT == 128
#define SCAN_CH 4096   // elements per scan block (256 threads x 16)
#define NP1 256        // coarse pass blocks
#define BSH 7          // bucket = dst >> 7  (128 nodes per bucket)
#define BNODES 128

typedef __bf16 bf16x8 __attribute__((ext_vector_type(8)));
typedef float  f32x4  __attribute__((ext_vector_type(4)));

__device__ __forceinline__ __bf16 f2bf(float f) { return (__bf16)f; }

// ---------------------------------------------------------------------------
// Dispatch 1 (block-specialized, NO global atomics anywhere):
//   blocks [0, NP1): coarse bucket histogram in LDS -> cnts[bucket][block]
//   blocks [NP1, .): MFMA GEMM y = x @ W^T, W converted inline (R13 pattern)
// ---------------------------------------------------------------------------
__global__ __launch_bounds__(256) void gemm_hist_kernel(
    const float* __restrict__ x, const float* __restrict__ W,
    __bf16* __restrict__ y, int M,
    const int* __restrict__ dst, int* __restrict__ cnts,
    int E, int chunk, int NBK)
{
    __shared__ int h[1024];            // NBK <= 1024
    const int tid = threadIdx.x;

    if (blockIdx.x < NP1) {
        for (int bk = tid; bk < NBK; bk += 256) h[bk] = 0;
        __syncthreads();
        int s = blockIdx.x * chunk;
        int e = s + chunk < E ? s + chunk : E;
        for (int i = s + tid; i < e; i += 256)
            atomicAdd(&h[dst[i] >> BSH], 1);          // LDS only
        __syncthreads();
        for (int bk = tid; bk < NBK; bk += 256)
            cnts[(size_t)bk * NP1 + blockIdx.x] = h[bk];
        return;
    }

    const int gb   = blockIdx.x - NP1;
    const int lane = tid & 63;
    const int wv   = tid >> 6;
    const int l15  = lane & 15;
    const int l4   = lane >> 4;
    const int row_base = gb * 128 + wv * 32;
    if (row_base >= M) return;

    f32x4 acc[2][8];
    #pragma unroll
    for (int mi = 0; mi < 2; ++mi)
        #pragma unroll
        for (int fn = 0; fn < 8; ++fn)
            #pragma unroll
            for (int c = 0; c < 4; ++c) acc[mi][fn][c] = 0.f;

    #pragma unroll
    for (int kb = 0; kb < 4; ++kb) {
        bf16x8 b[8];
        #pragma unroll
        for (int fn = 0; fn < 8; ++fn) {
            const float* wp = &W[(size_t)(fn * 16 + l15) * D + kb * 32 + l4 * 8];
            float4 w0 = *reinterpret_cast<const float4*>(wp);
            float4 w1 = *reinterpret_cast<const float4*>(wp + 4);
            b[fn][0]=f2bf(w0.x); b[fn][1]=f2bf(w0.y); b[fn][2]=f2bf(w0.z); b[fn][3]=f2bf(w0.w);
            b[fn][4]=f2bf(w1.x); b[fn][5]=f2bf(w1.y); b[fn][6]=f2bf(w1.z); b[fn][7]=f2bf(w1.w);
        }
        #pragma unroll
        for (int mi = 0; mi < 2; ++mi) {
            int row = row_base + mi * 16 + l15;
            int rc  = row < M ? row : M - 1;          // clamp; stores guarded
            const f32x4* ap = reinterpret_cast<const f32x4*>(
                                   &x[(size_t)rc * D + kb * 32 + l4 * 8]);
            f32x4 v0 = ap[0];
            f32x4 v1 = ap[1];
            bf16x8 a;
            a[0]=f2bf(v0[0]); a[1]=f2bf(v0[1]); a[2]=f2bf(v0[2]); a[3]=f2bf(v0[3]);
            a[4]=f2bf(v1[0]); a[5]=f2bf(v1[1]); a[6]=f2bf(v1[2]); a[7]=f2bf(v1[3]);
            #pragma unroll
            for (int fn = 0; fn < 8; ++fn)
                acc[mi][fn] = __builtin_amdgcn_mfma_f32_16x16x32_bf16(
                                  a, b[fn], acc[mi][fn], 0, 0, 0);
        }
    }

    // C/D layout: col = lane&15 (+fn*16), row = (lane>>4)*4 + r (+mi*16)
    #pragma unroll
    for (int mi = 0; mi < 2; ++mi)
        #pragma unroll
        for (int r = 0; r < 4; ++r) {
            int row = row_base + mi * 16 + l4 * 4 + r;
            if (row >= M) continue;
            #pragma unroll
            for (int fn = 0; fn < 8; ++fn)
                y[(size_t)row * D + fn * 16 + l15] = f2bf(acc[mi][fn][r]);
        }
}

// ---------------------------------------------------------------------------
// Scan of cnts -> coffs (exclusive prefix over NC = NBK*NP1 values).
// ---------------------------------------------------------------------------
__global__ __launch_bounds__(256) void scan_part_kernel(
    const int* __restrict__ cnts, int* __restrict__ bsum, int NC)
{
    __shared__ int wred[4];
    const int tid  = threadIdx.x;
    const int lane = tid & 63;
    const int wid  = tid >> 6;
    int off = blockIdx.x * SCAN_CH + tid * 16;
    int s = 0;
    #pragma unroll
    for (int i = 0; i < 16; ++i) {
        int idx = off + i;
        if (idx < NC) s += cnts[idx];
    }
    #pragma unroll
    for (int d = 32; d >= 1; d >>= 1) s += __shfl_xor(s, d, 64);
    if (lane == 0) wred[wid] = s;
    __syncthreads();
    if (tid == 0) bsum[blockIdx.x] = wred[0] + wred[1] + wred[2] + wred[3];
}

__global__ __launch_bounds__(256) void scan_write_kernel(
    const int* __restrict__ cnts, const int* __restrict__ bsum,
    int* __restrict__ coffs, int NC)
{
    __shared__ int boff_s;
    __shared__ int wsum[4];
    const int b    = blockIdx.x;
    const int tid  = threadIdx.x;
    const int lane = tid & 63;
    const int wid  = tid >> 6;

    if (wid == 0) {
        int v = (lane < b) ? bsum[lane] : 0;   // NB <= 64
        #pragma unroll
        for (int d = 32; d >= 1; d >>= 1) v += __shfl_xor(v, d, 64);
        if (lane == 0) boff_s = v;
    }
    __syncthreads();

    int off = b * SCAN_CH + tid * 16;
    int v[16];
    int s = 0;
    #pragma unroll
    for (int i = 0; i < 16; ++i) {
        int idx = off + i;
        v[i] = (idx < NC) ? cnts[idx] : 0;
        s += v[i];
    }
    int ssum = s;
    #pragma unroll
    for (int d = 1; d < 64; d <<= 1) {
        int t = __shfl_up(ssum, d, 64);
        if (lane >= d) ssum += t;
    }
    if (lane == 63) wsum[wid] = ssum;
    __syncthreads();
    int woff = 0;
    for (int w = 0; w < wid; ++w) woff += wsum[w];

    int run = boff_s + woff + ssum - s;
    #pragma unroll
    for (int i = 0; i < 16; ++i) {
        int idx = off + i;
        if (idx < NC) coffs[idx] = run;
        run += v[i];
    }
}

// ---------------------------------------------------------------------------
// Pass 1b: scatter edges into bucket-contiguous arrays via LDS cursors.
// ---------------------------------------------------------------------------
__global__ __launch_bounds__(256) void p1b_kernel(
    const int* __restrict__ src, const int* __restrict__ dst,
    const float* __restrict__ ew, const int* __restrict__ coffs,
    int* __restrict__ cDst, int2* __restrict__ cSW, int E, int chunk, int NBK)
{
    __shared__ int h[1024];
    const int tid = threadIdx.x;
    const int k   = blockIdx.x;
    for (int bk = tid; bk < NBK; bk += 256)
        h[bk] = coffs[(size_t)bk * NP1 + k];
    __syncthreads();
    int s = k * chunk;
    int e = s + chunk < E ? s + chunk : E;
    for (int i = s + tid; i < e; i += 256) {
        int d  = dst[i];
        int p  = atomicAdd(&h[d >> BSH], 1);     // LDS atomic-return
        cDst[p] = d;
        cSW[p]  = make_int2(src[i] * (D / 2), __float_as_int(ew[i]));
    }
}

// ---------------------------------------------------------------------------
// Bucket-gather: one block per 128-node bucket.  fp32 accumulators in 64KB
// LDS; stream bucket edges (8-deep MLP, scalar bounds), ds_add_f32
// accumulate; epilogue adds bias and writes out coalesced.
// ---------------------------------------------------------------------------
__global__ __launch_bounds__(256) void bgather_kernel(
    const __bf16* __restrict__ y, const int* __restrict__ cDst,
    const int2* __restrict__ cSW, const int* __restrict__ coffs,
    const float* __restrict__ bias, float* __restrict__ out,
    int M, int E, int NBK)
{
    __shared__ float acc[BNODES * D];          // 64 KB
    const int tid = threadIdx.x;
    const int b   = blockIdx.x;
    const int n0  = b << BSH;

    f32x4 z4 = {0.f, 0.f, 0.f, 0.f};
    #pragma unroll
    for (int i = 0; i < 16; ++i)
        *reinterpret_cast<f32x4*>(&acc[(tid + i * 256) * 4]) = z4;
    __syncthreads();

    const int e0 = coffs[(size_t)b * NP1];
    const int e1 = (b + 1 < NBK) ? coffs[(size_t)(b + 1) * NP1] : E;

    const unsigned* yb = reinterpret_cast<const unsigned*>(y);
    const int wv   = tid >> 6;
    const int lane = tid & 63;
    const int total = e1 - e0;
    const int per   = (total + 3) >> 2;
    int ws = e0 + wv * per;
    int we = ws + per < e1 ? ws + per : e1;
    ws = __builtin_amdgcn_readfirstlane(ws);
    we = __builtin_amdgcn_readfirstlane(we);

    for (int i = ws; i < we; i += 8) {
        int2 e[8];
        int  nd[8];
        #pragma unroll
        for (int t = 0; t < 8; ++t) {
            int idx  = i + t;
            int idxc = idx < we ? idx : we - 1;
            e[t]  = cSW[idxc];
            nd[t] = cDst[idxc] & (BNODES - 1);
        }
        unsigned p[8];
        #pragma unroll
        for (int t = 0; t < 8; ++t)
            p[t] = yb[(unsigned)e[t].x + lane];
        #pragma unroll
        for (int t = 0; t < 8; ++t) {
            float w = (i + t < we) ? __int_as_float(e[t].y) : 0.f;
            float fx = __uint_as_float(p[t] << 16) * w;
            float fy = __uint_as_float(p[t] & 0xFFFF0000u) * w;
            atomicAdd(&acc[nd[t] * D + 2 * lane], fx);      // ds_add_f32
            atomicAdd(&acc[nd[t] * D + 2 * lane + 1], fy);
        }
    }
    __syncthreads();

    // epilogue: out = acc + bias, fully coalesced float4 stores
    #pragma unroll
    for (int i = 0; i < 16; ++i) {
        int idx = tid + i * 256;        // float4 index, 4096 total
        int r   = idx >> 5;             // 32 float4 per row
        int c4  = idx & 31;
        int row = n0 + r;
        if (row < M) {
            f32x4 v  = *reinterpret_cast<f32x4*>(&acc[idx * 4]);
            f32x4 bv = *reinterpret_cast<const f32x4*>(&bias[c4 * 4]);
            v[0] += bv[0]; v[1] += bv[1]; v[2] += bv[2]; v[3] += bv[3];
            *reinterpret_cast<f32x4*>(&out[(size_t)row * D + c4 * 4]) = v;
        }
    }
}

extern "C" void kernel_launch(void* const* d_in, const int* in_sizes, int n_in,
                              void* d_out, int out_size, void* d_ws, size_t ws_size,
                              hipStream_t stream) {
    const float* x   = (const float*)d_in[0];
    const float* ew  = (const float*)d_in[1];
    const int*   src = (const int*)d_in[2];
    const int*   dst = (const int*)d_in[3];
    const float* W   = (const float*)d_in[4];
    const float* b   = (const float*)d_in[5];
    float*       out = (float*)d_out;

    const int E     = in_sizes[2];                  // 640000
    const int M     = out_size / D;                 // 100000 nodes
    const int NBK   = (M + BNODES - 1) >> BSH;      // 782 buckets
    const int NC    = NBK * NP1;                    // 200192
    const int chunk = (E + NP1 - 1) / NP1;          // 2500
    const int NB    = (NC + SCAN_CH - 1) / SCAN_CH; // 49 (<=64)

    // ws layout: y bf16[M*D] | cnts[NC] | coffs[NC] | cDst[E] | cSW[E] | bsum[NB]
    char* p = (char*)d_ws;
    __bf16* y     = (__bf16*)p;            p += (size_t)M * D * 2;
    int*    cnts  = (int*)p;               p += (size_t)NC * 4;
    int*    coffs = (int*)p;               p += (size_t)NC * 4;
    int*    cDst  = (int*)p;               p += (size_t)E * 4;
    int2*   cSW   = (int2*)p;              p += (size_t)E * 8;
    int*    bsum  = (int*)p;

    // 1) [coarse hist (0..NP1)] || [MFMA GEMM, inline W (NP1..)]
    int gemmBlocks = (M + 127) / 128;
    gemm_hist_kernel<<<NP1 + gemmBlocks, 256, 0, stream>>>(
        x, W, y, M, dst, cnts, E, chunk, NBK);

    // 2-3) scan cnts -> coffs
    scan_part_kernel<<<NB, 256, 0, stream>>>(cnts, bsum, NC);
    scan_write_kernel<<<NB, 256, 0, stream>>>(cnts, bsum, coffs, NC);

    // 4) bucket scatter (LDS cursors)
    p1b_kernel<<<NP1, 256, 0, stream>>>(src, dst, ew, coffs, cDst, cSW, E, chunk, NBK);

    // 5) bucket-gather: LDS fp32 accumulate + bias + coalesced out
    bgather_kernel<<<NBK, 256, 0, stream>>>(y, cDst, cSW, coffs, b, out, M, E, NBK);
}

// Round 22
// 116.357 us; speedup vs baseline: 5.3293x; 5.3293x over previous
//
#include <hip/hip_runtime.h>
#include <hip/hip_bf16.h>

#define D 128          // D_IN == D_OUT == 128
#define SCAN_CH 4096   // elements per scan block (256 threads x 16)

typedef __bf16 bf16x8 __attribute__((ext_vector_type(8)));
typedef float  f32x4  __attribute__((ext_vector_type(4)));
typedef float  f32x2  __attribute__((ext_vector_type(2)));

__device__ __forceinline__ __bf16 f2bf(float f) { return (__bf16)f; }
__device__ __forceinline__ int pad8(int v) { return (v + 7) & ~7; }

// ---------------------------------------------------------------------------
// Prep: pack W into MFMA B-fragment order (bf16), zero cnt, zero bins.
// ---------------------------------------------------------------------------
__global__ __launch_bounds__(256) void prep_kernel(
    const float* __restrict__ W, __bf16* __restrict__ wb,
    int* __restrict__ cnt, int M, int4* __restrict__ bins4, long nbin4)
{
    long t    = (long)blockIdx.x * 256 + threadIdx.x;
    long nthr = (long)gridDim.x * 256;

    for (long i = t; i < nbin4; i += nthr) bins4[i] = make_int4(0, 0, 0, 0);
    for (long i = t; i < M; i += nthr) cnt[i] = 0;

    if (t < 2048) {
        int lane = (int)t & 63;
        int frag = (int)t >> 6;                      // 0..31 = kb*8+fn
        int kb = frag >> 3, fn = frag & 7;
        int n  = fn * 16 + (lane & 15);
        int k0 = kb * 32 + (lane >> 4) * 8;
        const float* src = &W[(size_t)n * D + k0];
        float4 v0 = *reinterpret_cast<const float4*>(src);
        float4 v1 = *reinterpret_cast<const float4*>(src + 4);
        bf16x8 o;
        o[0]=f2bf(v0.x); o[1]=f2bf(v0.y); o[2]=f2bf(v0.z); o[3]=f2bf(v0.w);
        o[4]=f2bf(v1.x); o[5]=f2bf(v1.y); o[6]=f2bf(v1.z); o[7]=f2bf(v1.w);
        *reinterpret_cast<bf16x8*>(&wb[((size_t)frag * 64 + lane) * 8]) = o;
    }
}

// ---------------------------------------------------------------------------
// Histogram (R12-proven, ~13us): one edge per thread, rank recorded.
// ---------------------------------------------------------------------------
__global__ __launch_bounds__(256) void hist_kernel(
    const int* __restrict__ dst, int* __restrict__ cnt,
    int* __restrict__ rank, int E)
{
    int e = blockIdx.x * 256 + threadIdx.x;
    if (e < E) {
        int d = __builtin_nontemporal_load(&dst[e]);
        rank[e] = atomicAdd(&cnt[d], 1);
    }
}

// ---------------------------------------------------------------------------
// Two-kernel scan over PADDED counts (pad8); pads pre-zeroed by prep.
// ---------------------------------------------------------------------------
__global__ __launch_bounds__(256) void scan_part_kernel(
    const int* __restrict__ cnt, int* __restrict__ bsum, int N)
{
    __shared__ int wred[4];
    const int tid  = threadIdx.x;
    const int lane = tid & 63;
    const int wid  = tid >> 6;
    int off = blockIdx.x * SCAN_CH + tid * 16;
    int s = 0;
    #pragma unroll
    for (int i = 0; i < 16; ++i) {
        int idx = off + i;
        if (idx < N) s += pad8(cnt[idx]);
    }
    #pragma unroll
    for (int d = 32; d >= 1; d >>= 1) s += __shfl_xor(s, d, 64);
    if (lane == 0) wred[wid] = s;
    __syncthreads();
    if (tid == 0) bsum[blockIdx.x] = wred[0] + wred[1] + wred[2] + wred[3];
}

__global__ __launch_bounds__(256) void scan_write_kernel(
    const int* __restrict__ cnt, const int* __restrict__ bsum,
    int* __restrict__ base, int N, int NB)
{
    __shared__ int boff_s;
    __shared__ int wsum[4];
    const int b    = blockIdx.x;
    const int tid  = threadIdx.x;
    const int lane = tid & 63;
    const int wid  = tid >> 6;

    if (wid == 0) {
        int v = (lane < b) ? bsum[lane] : 0;   // NB <= 64
        #pragma unroll
        for (int d = 32; d >= 1; d >>= 1) v += __shfl_xor(v, d, 64);
        if (lane == 0) boff_s = v;
    }
    __syncthreads();

    int off = b * SCAN_CH + tid * 16;
    int v[16];
    int s = 0;
    #pragma unroll
    for (int i = 0; i < 16; ++i) {
        int idx = off + i;
        v[i] = (idx < N) ? pad8(cnt[idx]) : 0;
        s += v[i];
    }
    int ssum = s;
    #pragma unroll
    for (int d = 1; d < 64; d <<= 1) {
        int t = __shfl_up(ssum, d, 64);
        if (lane >= d) ssum += t;
    }
    if (lane == 63) wsum[wid] = ssum;
    __syncthreads();
    int woff = 0;
    for (int w = 0; w < wid; ++w) woff += wsum[w];

    int run = boff_s + woff + ssum - s;
    #pragma unroll
    for (int i = 0; i < 16; ++i) {
        int idx = off + i;
        if (idx < N) base[idx] = run;
        if (idx == N - 1) base[N] = run + v[i];   // padded total
        run += v[i];
    }
}

// ---------------------------------------------------------------------------
// Fused bin || GEMM (block-specialized).  GEMM blocks FIRST (long half, 35us)
// so they start immediately; bin's 2500 light blocks trail into idle CUs.
//   blocks [0, gemmBlocks):   MFMA GEMM y = x @ W^T (R14 register form)
//   blocks [gemmBlocks, ...): bin: place edges at base[dst]+rank (no atomics)
// ---------------------------------------------------------------------------
__global__ __launch_bounds__(256) void bingemm_kernel(
    const float* __restrict__ x, const __bf16* __restrict__ wb,
    __bf16* __restrict__ y, int M, int gemmBlocks,
    const int* __restrict__ src, const int* __restrict__ dst,
    const float* __restrict__ ew, const int* __restrict__ base,
    const int* __restrict__ rank, int2* __restrict__ bins, int E)
{
    const int tid = threadIdx.x;

    if ((int)blockIdx.x >= gemmBlocks) {
        int e = ((int)blockIdx.x - gemmBlocks) * 256 + tid;
        if (e < E) {
            int d   = __builtin_nontemporal_load(&dst[e]);
            int sv  = __builtin_nontemporal_load(&src[e]);
            float w = __builtin_nontemporal_load(&ew[e]);
            int rk  = __builtin_nontemporal_load(&rank[e]);
            int p = base[d] + rk;
            bins[p] = make_int2(sv * (D / 2), __float_as_int(w));
        }
        return;
    }

    const int lane = tid & 63;
    const int wv   = tid >> 6;
    const int l15  = lane & 15;
    const int l4   = lane >> 4;
    const int row_base = blockIdx.x * 128 + wv * 32;
    if (row_base >= M) return;

    f32x4 acc[2][8];
    #pragma unroll
    for (int mi = 0; mi < 2; ++mi)
        #pragma unroll
        for (int fn = 0; fn < 8; ++fn)
            #pragma unroll
            for (int c = 0; c < 4; ++c) acc[mi][fn][c] = 0.f;

    #pragma unroll
    for (int kb = 0; kb < 4; ++kb) {
        bf16x8 b[8];
        #pragma unroll
        for (int fn = 0; fn < 8; ++fn)
            b[fn] = *reinterpret_cast<const bf16x8*>(
                        &wb[((size_t)(kb * 8 + fn) * 64 + lane) * 8]);
        #pragma unroll
        for (int mi = 0; mi < 2; ++mi) {
            int row = row_base + mi * 16 + l15;
            int rc  = row < M ? row : M - 1;        // clamp; stores guarded
            const f32x4* ap = reinterpret_cast<const f32x4*>(
                                   &x[(size_t)rc * D + kb * 32 + l4 * 8]);
            f32x4 v0 = ap[0];
            f32x4 v1 = ap[1];
            bf16x8 a;
            a[0]=f2bf(v0[0]); a[1]=f2bf(v0[1]); a[2]=f2bf(v0[2]); a[3]=f2bf(v0[3]);
            a[4]=f2bf(v1[0]); a[5]=f2bf(v1[1]); a[6]=f2bf(v1[2]); a[7]=f2bf(v1[3]);
            #pragma unroll
            for (int fn = 0; fn < 8; ++fn)
                acc[mi][fn] = __builtin_amdgcn_mfma_f32_16x16x32_bf16(
                                  a, b[fn], acc[mi][fn], 0, 0, 0);
        }
    }

    // C/D layout: col = lane&15 (+fn*16), row = (lane>>4)*4 + r (+mi*16)
    #pragma unroll
    for (int mi = 0; mi < 2; ++mi)
        #pragma unroll
        for (int r = 0; r < 4; ++r) {
            int row = row_base + mi * 16 + l4 * 4 + r;
            if (row >= M) continue;
            #pragma unroll
            for (int fn = 0; fn < 8; ++fn)
                y[(size_t)row * D + fn * 16 + l15] = f2bf(acc[mi][fn][r]);
        }
}

// ---------------------------------------------------------------------------
// Gather-sum from bf16 y: one wave per node, 8 edges in flight, NO bounds
// logic (buckets padded to x8 with {0, 0.0f} entries).  Scalar loop bounds.
// ---------------------------------------------------------------------------
__global__ __launch_bounds__(256) void gather_kernel(
    const __bf16* __restrict__ y, const int* __restrict__ base,
    const int2* __restrict__ bins, const float* __restrict__ bias,
    float* __restrict__ out, int N)
{
    int gw   = (blockIdx.x * 256 + threadIdx.x) >> 6;
    int lane = threadIdx.x & 63;
    if (gw >= N) return;

    const unsigned* yb = reinterpret_cast<const unsigned*>(y);  // 2 bf16 / uint
    const int b0 = __builtin_amdgcn_readfirstlane(base[gw]);
    const int b1 = __builtin_amdgcn_readfirstlane(base[gw + 1]);
    float accx = 0.f, accy = 0.f;

    for (int i = b0; i < b1; i += 8) {
        int2 e[8];
        #pragma unroll
        for (int t = 0; t < 8; ++t) e[t] = bins[i + t];
        unsigned p[8];
        #pragma unroll
        for (int t = 0; t < 8; ++t)
            p[t] = yb[(unsigned)e[t].x + lane];
        #pragma unroll
        for (int t = 0; t < 8; ++t) {
            float w = __int_as_float(e[t].y);
            accx += __uint_as_float(p[t] << 16) * w;
            accy += __uint_as_float(p[t] & 0xFFFF0000u) * w;
        }
    }

    float2 bv = *reinterpret_cast<const float2*>(&bias[lane * 2]);
    f32x2 o;
    o[0] = accx + bv.x;
    o[1] = accy + bv.y;
    __builtin_nontemporal_store(o, reinterpret_cast<f32x2*>(&out[(size_t)gw * D + lane * 2]));
}

extern "C" void kernel_launch(void* const* d_in, const int* in_sizes, int n_in,
                              void* d_out, int out_size, void* d_ws, size_t ws_size,
                              hipStream_t stream) {
    const float* x   = (const float*)d_in[0];
    const float* ew  = (const float*)d_in[1];
    const int*   src = (const int*)d_in[2];
    const int*   dst = (const int*)d_in[3];
    const float* W   = (const float*)d_in[4];
    const float* b   = (const float*)d_in[5];
    float*       out = (float*)d_out;

    const int E  = in_sizes[2];                 // 640000
    const int M  = out_size / D;                // 100000 nodes
    const int NB = (M + SCAN_CH - 1) / SCAN_CH; // 25 (<=64 required)
    const size_t BIN_CAP = ((size_t)E + 7 * (size_t)M + 8) & ~(size_t)1;

    // ws layout: y bf16[M*D] | wb bf16[32*64*8] | bins int2[BIN_CAP] |
    //            base[M+1] | cnt[M] | rank[E] | bsum[NB]
    char* p = (char*)d_ws;
    __bf16* y    = (__bf16*)p;             p += (size_t)M * D * 2;
    __bf16* wb   = (__bf16*)p;             p += (size_t)32 * 64 * 8 * 2;
    int2*   bins = (int2*)p;               p += BIN_CAP * 8;
    int*    base = (int*)p;                p += (size_t)(M + 1) * 4;
    int*    cnt  = (int*)p;                p += (size_t)M * 4;
    int*    rank = (int*)p;                p += (size_t)E * 4;
    int*    bsum = (int*)p;

    // 1) pack W, zero cnt, zero bins
    prep_kernel<<<512, 256, 0, stream>>>(W, wb, cnt, M,
                                         (int4*)bins, (long)(BIN_CAP / 2));

    // 2) histogram (rank recorded) — ~13us standalone (R12)
    hist_kernel<<<(E + 255) / 256, 256, 0, stream>>>(dst, cnt, rank, E);

    // 3-4) scan over padded counts
    scan_part_kernel<<<NB, 256, 0, stream>>>(cnt, bsum, M);
    scan_write_kernel<<<NB, 256, 0, stream>>>(cnt, bsum, base, M, NB);

    // 5) fused: GEMM blocks first, bin blocks trail (independent work)
    int gemmBlocks = (M + 127) / 128;           // 782
    int binBlocks  = (E + 255) / 256;           // 2500
    bingemm_kernel<<<gemmBlocks + binBlocks, 256, 0, stream>>>(
        x, wb, y, M, gemmBlocks, src, dst, ew, base, rank, bins, E);

    // 6) out[n] = sum_{e in node n} y[src_e] * w_e + bias
    gather_kernel<<<(M * 64 + 255) / 256, 256, 0, stream>>>(y, base, bins, b, out, M);
}